// Round 2
// baseline (850.921 us; speedup 1.0000x reference)
//
#include <hip/hip_runtime.h>
#include <hip/hip_cooperative_groups.h>
namespace cg = cooperative_groups;

#define EPS 1e-5f
constexpr int HD = 128;   // node feature / hidden dim
constexpr int FCD = 64;   // fc hidden dim
constexpr int RREP = 32;  // BN-stat atomic replicas (contention / 32)
constexpr int R2 = 8;     // fc-stat atomic replicas

typedef __attribute__((ext_vector_type(8))) short short8;
typedef __attribute__((ext_vector_type(4))) float floatx4;

// ---------- bf16 helpers ----------
__device__ inline ushort f2bf(float f){
  union{float f; unsigned u;} v; v.f = f;
  unsigned r = v.u + 0x7FFFu + ((v.u >> 16) & 1u);
  return (ushort)(r >> 16);
}
__device__ inline float bflo(unsigned u){ union{unsigned i; float f;} v; v.i = u << 16;        return v.f; }
__device__ inline float bfhi(unsigned u){ union{unsigned i; float f;} v; v.i = u & 0xFFFF0000u; return v.f; }
__device__ inline float bf2f(ushort u){ union{unsigned i; float f;} v; v.i = ((unsigned)u) << 16; return v.f; }

// ---------- params ----------
struct Params {
  const float* x; const int* esrc; const int* edst; const int* batch;
  const float* W1; const float* g1; const float* be1;
  const float* W2; const float* g2; const float* be2;
  const float* W3; const float* g3; const float* be3;
  const float* fcW1; const float* fcb1; const float* fcg1; const float* fcbe1;
  const float* fcW2; const float* fcb2;
  float* out;
  int* bucketHist; int* bucketCursor; int* batchPtr;
  int2* tmp; int* rowptr; int* csrc; float* dis;
  ushort* HWb; ushort* AGG; ushort* Wf;
  float* sumsRep;   // [3][RREP][2*HD]
  float* sums2Rep;  // [R2][2*FCD]
  float* zbuf;      // [G][FCD]
  int* zeroBase; int zeroWords;
  int N, E, G, nEB, NB;
  float invN, invG;
};

// ---------- LDS phase structs (union'd in the mega kernel) ----------
struct SmHist   { int h[256]; };
struct SmBucket { int h[256], ls[256], cur[256], gb[256], base[256], wt[4];
                  int2 staged[4096]; unsigned char bos[4096]; };
struct SmCsr    { int h[256], ls[256], cur[256], base[256], wt[4]; int stagedSrc[6144]; };
struct SmGather { float2 sm[4][HD]; };
struct SmGemm   { float aL[HD], bL[HD]; };
struct SmHead   { float sm[4][HD]; float prow[HD]; };
union  SMem { SmHist hist; SmBucket bk; SmCsr cs; SmGather ga; SmGemm ge; SmHead hd; };

// ---------- phase: zero workspace counters/stats ----------
__device__ __forceinline__ void ph_zero(const Params& P, int gtid, int gstride){
  for (int i = gtid; i < P.zeroWords; i += gstride) P.zeroBase[i] = 0;
}

// ---------- phase: edge histogram + batchPtr + W pack ----------
__device__ __forceinline__ void ph_setup(const Params& P, SmHist& S, int bid, int nblk){
  int t = threadIdx.x;
  for (int c = bid; c < P.nEB; c += nblk){
    S.h[t] = 0;
    __syncthreads();
    int base = c*4096;
    #pragma unroll
    for (int k = 0; k < 16; ++k){
      int e = base + k*256 + t;
      if (e < P.E) atomicAdd(&S.h[P.edst[e] >> 8], 1);
    }
    __syncthreads();
    if (S.h[t]) atomicAdd(&P.bucketHist[t], S.h[t]);
    __syncthreads();
  }
  int gtid = bid*256 + t, gs = nblk*256;
  for (int i = gtid; i < P.N; i += gs){
    int bb = P.batch[i];
    int prev = (i == 0) ? -1 : P.batch[i-1];
    for (int g = prev + 1; g <= bb; ++g) P.batchPtr[g] = i;
    if (i == P.N-1)
      for (int g = bb + 1; g <= P.G; ++g) P.batchPtr[g] = P.N;
  }
  for (int idx = gtid; idx < 3*HD*HD; idx += gs){
    int l = idx >> 14, r = idx & 16383;
    const float* Ws = (l==0) ? P.W1 : (l==1) ? P.W2 : P.W3;
    int k = r >> 7, n = r & 127;
    float w = Ws[r];
    int kb = k >> 5, q = (k >> 3) & 3, jj = k & 7;
    int nt = n >> 4, col = n & 15;
    P.Wf[(size_t)l*16384 + (((size_t)(kb*8 + nt)*64 + q*16 + col)*8 + jj)] = f2bf(w);
  }
}

// full 256-entry exclusive scan of bucketHist into LDS baseArr (redundant per block)
__device__ __forceinline__ void scan_hist(const int* hist, int* baseArr, int* wt){
  int t = threadIdx.x, lane = t & 63, w = t >> 6;
  int v = hist[t];
  int incl = v;
  #pragma unroll
  for (int o = 1; o < 64; o <<= 1){
    int x = __shfl_up(incl, o, 64);
    if (lane >= o) incl += x;
  }
  if (lane == 63) wt[w] = incl;
  __syncthreads();
  int woff = 0;
  for (int i = 0; i < w; ++i) woff += wt[i];
  baseArr[t] = woff + incl - v;
  __syncthreads();
}

// ---------- phase: LDS-staged bucket scatter ----------
__device__ __forceinline__ void ph_bucket(const Params& P, SmBucket& S, int bid, int nblk){
  int t = threadIdx.x, lane = t & 63, w = t >> 6;
  scan_hist(P.bucketHist, S.base, S.wt);
  for (int c = bid; c < P.nEB; c += nblk){
    int base = c*4096;
    int2 ed[16]; int bk_[16];
    S.h[t] = 0;
    __syncthreads();
    #pragma unroll
    for (int k = 0; k < 16; ++k){
      int e = base + k*256 + t;
      if (e < P.E){
        ed[k] = make_int2(P.esrc[e], P.edst[e]);
        bk_[k] = ed[k].y >> 8;
        atomicAdd(&S.h[bk_[k]], 1);
      } else bk_[k] = -1;
    }
    __syncthreads();
    int v = S.h[t];
    int incl = v;
    #pragma unroll
    for (int o = 1; o < 64; o <<= 1){
      int x = __shfl_up(incl, o, 64);
      if (lane >= o) incl += x;
    }
    if (lane == 63) S.wt[w] = incl;
    __syncthreads();
    int woff = 0;
    for (int i = 0; i < w; ++i) woff += S.wt[i];
    S.ls[t] = woff + incl - v;
    S.cur[t] = S.ls[t];
    if (v > 0) S.gb[t] = S.base[t] + atomicAdd(&P.bucketCursor[t], v);
    __syncthreads();
    #pragma unroll
    for (int k = 0; k < 16; ++k){
      if (bk_[k] >= 0){
        int lp = atomicAdd(&S.cur[bk_[k]], 1);
        S.staged[lp] = ed[k];
        S.bos[lp] = (unsigned char)bk_[k];
      }
    }
    __syncthreads();
    int nvalid = min(4096, P.E - base);
    #pragma unroll
    for (int k = 0; k < 16; ++k){
      int i = k*256 + t;
      if (i < nvalid){
        int b = S.bos[i];
        P.tmp[S.gb[b] + (i - S.ls[b])] = S.staged[i];
      }
    }
    __syncthreads();
  }
}

// ---------- phase: per-bucket exact-dst grouping -> rowptr/dis/csrc ----------
__device__ __forceinline__ void ph_csr(const Params& P, SmCsr& S, int bid, int nblk){
  int t = threadIdx.x, lane = t & 63, w = t >> 6;
  scan_hist(P.bucketHist, S.base, S.wt);
  for (int b = bid; b < P.NB; b += nblk){
    int ebase = S.base[b];
    int cnt = P.bucketHist[b];
    int node0 = b << 8;
    S.h[t] = 0;
    __syncthreads();
    for (int i = t; i < cnt; i += 256){
      int2 e = P.tmp[ebase + i];
      atomicAdd(&S.h[e.y - node0], 1);
    }
    __syncthreads();
    int v = S.h[t];
    int incl = v;
    #pragma unroll
    for (int o = 1; o < 64; o <<= 1){
      int x = __shfl_up(incl, o, 64);
      if (lane >= o) incl += x;
    }
    if (lane == 63) S.wt[w] = incl;
    __syncthreads();
    int woff = 0;
    for (int i = 0; i < w; ++i) woff += S.wt[i];
    int ex = woff + incl - v;
    S.ls[t] = ex; S.cur[t] = ex;
    int d = node0 + t;
    if (d < P.N){
      P.rowptr[d+1] = ebase + ex + v;
      P.dis[d] = rsqrtf((float)v + 1.0f);
    }
    if (b == 0 && t == 0) P.rowptr[0] = 0;
    __syncthreads();
    for (int i = t; i < cnt; i += 256){
      int2 e = P.tmp[ebase + i];
      int lp = atomicAdd(&S.cur[e.y - node0], 1);
      S.stagedSrc[lp] = e.x;
    }
    __syncthreads();
    for (int i = t; i < cnt; i += 256)
      P.csrc[ebase + i] = S.stagedSrc[i];
    __syncthreads();
  }
}

// ---------- phase: bf16 MFMA GEMM, fused BN-affine+ReLU on A, dis-scale on out ----
template<int MODE>
__device__ __forceinline__ void ph_gemm(const Params& P, SmGemm& S, int bid, int nblk,
                                        const void* Av, const ushort* Wf,
                                        const float* rep, const float* g, const float* be,
                                        ushort* O){
  int tid = threadIdx.x;
  if (MODE){
    if (tid < HD){
      float sS = 0.f, sQ = 0.f;
      for (int r = 0; r < RREP; ++r){
        sS += rep[(size_t)r*2*HD + tid];
        sQ += rep[(size_t)r*2*HD + HD + tid];
      }
      float m = sS*P.invN;
      float var = fmaxf(sQ*P.invN - m*m, 0.f);
      float Ac = g[tid]*rsqrtf(var + EPS);
      S.aL[tid] = Ac; S.bL[tid] = be[tid] - m*Ac;
    }
    __syncthreads();
  }
  int lane = tid & 63, wave = tid >> 6;
  int quad = lane >> 4, r16 = lane & 15;
  int nT = (P.N + 63) >> 6;
  for (int tile = bid; tile < nT; tile += nblk){
    int row = tile*64 + wave*16 + r16;
    int rowc = min(row, P.N-1);
    floatx4 acc[8] = {};
    #pragma unroll
    for (int kb = 0; kb < 4; ++kb){
      int k0 = kb*32 + quad*8;
      short8 af;
      if (MODE){
        const ushort* Arow = (const ushort*)Av + (size_t)rowc*HD;
        short8 raw = *(const short8*)(Arow + k0);
        #pragma unroll
        for (int jj = 0; jj < 8; ++jj){
          float f = bf2f((ushort)raw[jj]);
          f = fmaxf(f*S.aL[k0+jj] + S.bL[k0+jj], 0.f);
          af[jj] = (short)f2bf(f);
        }
      } else {
        const float* Arow = (const float*)Av + (size_t)rowc*HD;
        float4 x0 = *(const float4*)(Arow + k0);
        float4 x1 = *(const float4*)(Arow + k0 + 4);
        af[0] = (short)f2bf(x0.x); af[1] = (short)f2bf(x0.y);
        af[2] = (short)f2bf(x0.z); af[3] = (short)f2bf(x0.w);
        af[4] = (short)f2bf(x1.x); af[5] = (short)f2bf(x1.y);
        af[6] = (short)f2bf(x1.z); af[7] = (short)f2bf(x1.w);
      }
      const ushort* wp = Wf + ((size_t)(kb*8)*64 + lane)*8;
      #pragma unroll
      for (int nt = 0; nt < 8; ++nt){
        short8 bf = *(const short8*)(wp + (size_t)nt*64*8);
        acc[nt] = __builtin_amdgcn_mfma_f32_16x16x32_bf16(af, bf, acc[nt], 0, 0, 0);
      }
    }
    int rbase = tile*64 + wave*16 + quad*4;
    float ds[4];
    #pragma unroll
    for (int r = 0; r < 4; ++r) ds[r] = P.dis[min(rbase + r, P.N-1)];
    #pragma unroll
    for (int nt = 0; nt < 8; ++nt){
      #pragma unroll
      for (int r = 0; r < 4; ++r){
        int rr = rbase + r;
        if (rr < P.N) O[(size_t)rr*HD + nt*16 + r16] = f2bf(acc[nt][r]*ds[r]);
      }
    }
  }
}

// ---------- phase: edge aggregation + BN stats (replicated atomics) ----------
__device__ __forceinline__ void ph_gather(const Params& P, SmGather& S, int bid, int nblk,
                                          const ushort* hw, ushort* agg, float* repOut){
  int grp = threadIdx.x >> 4, j = threadIdx.x & 15;
  int wave = threadIdx.x >> 6, lane = threadIdx.x & 63;
  int nCh = (P.N + 15) >> 4;
  float accS = 0.f, accQ = 0.f;
  for (int ch = bid; ch < nCh; ch += nblk){
    int i = ch*16 + grp;
    bool valid = (i < P.N);
    int ic = valid ? i : P.N-1;
    uint4 q = ((const uint4*)(hw + (size_t)ic*HD))[j];
    float a[8];
    a[0] = bflo(q.x); a[1] = bfhi(q.x);
    a[2] = bflo(q.y); a[3] = bfhi(q.y);
    a[4] = bflo(q.z); a[5] = bfhi(q.z);
    a[6] = bflo(q.w); a[7] = bfhi(q.w);
    int e = P.rowptr[ic], e1 = P.rowptr[ic+1];
    #define ADD8(Q) \
      a[0] += bflo(Q.x); a[1] += bfhi(Q.x); \
      a[2] += bflo(Q.y); a[3] += bfhi(Q.y); \
      a[4] += bflo(Q.z); a[5] += bfhi(Q.z); \
      a[6] += bflo(Q.w); a[7] += bfhi(Q.w);
    while (e < e1 && (e & 3)){
      uint4 qq = ((const uint4*)(hw + (size_t)P.csrc[e]*HD))[j];
      ADD8(qq);
      e++;
    }
    int4 c0, c1;
    if (e + 8 <= e1){
      c0 = *(const int4*)&P.csrc[e];
      c1 = *(const int4*)&P.csrc[e+4];
    }
    while (e + 8 <= e1){
      int en = e + 8;
      int4 n0, n1;
      if (en + 8 <= e1){
        n0 = *(const int4*)&P.csrc[en];
        n1 = *(const int4*)&P.csrc[en+4];
      }
      uint4 q0 = ((const uint4*)(hw + (size_t)c0.x*HD))[j];
      uint4 q1 = ((const uint4*)(hw + (size_t)c0.y*HD))[j];
      uint4 q2 = ((const uint4*)(hw + (size_t)c0.z*HD))[j];
      uint4 q3 = ((const uint4*)(hw + (size_t)c0.w*HD))[j];
      uint4 q4 = ((const uint4*)(hw + (size_t)c1.x*HD))[j];
      uint4 q5 = ((const uint4*)(hw + (size_t)c1.y*HD))[j];
      uint4 q6 = ((const uint4*)(hw + (size_t)c1.z*HD))[j];
      uint4 q7 = ((const uint4*)(hw + (size_t)c1.w*HD))[j];
      ADD8(q0); ADD8(q1); ADD8(q2); ADD8(q3);
      ADD8(q4); ADD8(q5); ADD8(q6); ADD8(q7);
      c0 = n0; c1 = n1; e = en;
    }
    if (e + 4 <= e1){
      int4 tt = *(const int4*)&P.csrc[e];
      uint4 q0 = ((const uint4*)(hw + (size_t)tt.x*HD))[j];
      uint4 q1 = ((const uint4*)(hw + (size_t)tt.y*HD))[j];
      uint4 q2 = ((const uint4*)(hw + (size_t)tt.z*HD))[j];
      uint4 q3 = ((const uint4*)(hw + (size_t)tt.w*HD))[j];
      ADD8(q0); ADD8(q1); ADD8(q2); ADD8(q3);
      e += 4;
    }
    for (; e < e1; ++e){
      uint4 qq = ((const uint4*)(hw + (size_t)P.csrc[e]*HD))[j];
      ADD8(qq);
    }
    #undef ADD8
    float sc = P.dis[ic];
    #pragma unroll
    for (int k = 0; k < 8; ++k) a[k] *= sc;
    if (valid){
      uint4 o;
      o.x = (unsigned)f2bf(a[0]) | ((unsigned)f2bf(a[1]) << 16);
      o.y = (unsigned)f2bf(a[2]) | ((unsigned)f2bf(a[3]) << 16);
      o.z = (unsigned)f2bf(a[4]) | ((unsigned)f2bf(a[5]) << 16);
      o.w = (unsigned)f2bf(a[6]) | ((unsigned)f2bf(a[7]) << 16);
      ((uint4*)(agg + (size_t)i*HD))[j] = o;
    }
    float z = valid ? 1.f : 0.f;
    #pragma unroll
    for (int k = 0; k < 8; ++k){
      float s = a[k]*z, qq = a[k]*a[k]*z;
      s  += __shfl_xor(s, 16);  s  += __shfl_xor(s, 32);
      qq += __shfl_xor(qq, 16); qq += __shfl_xor(qq, 32);
      if (lane < 16) S.sm[wave][lane*8 + k] = make_float2(s, qq);
    }
    __syncthreads();
    int t = threadIdx.x;
    if (t < HD){
      float2 r0 = S.sm[0][t], r1 = S.sm[1][t], r2 = S.sm[2][t], r3 = S.sm[3][t];
      accS += r0.x + r1.x + r2.x + r3.x;
      accQ += r0.y + r1.y + r2.y + r3.y;
    }
    __syncthreads();
  }
  if (threadIdx.x < HD){
    float* d = repOut + (size_t)(bid & (RREP-1))*(2*HD);
    atomicAdd(&d[threadIdx.x], accS);
    atomicAdd(&d[HD + threadIdx.x], accQ);
  }
}

// ---------- phase: per-graph mean pool (BN3+ReLU) + fc1 + z-stats ----------
__device__ __forceinline__ void ph_head(const Params& P, SmHead& S, int bid, int nblk){
  int tid = threadIdx.x;
  int j = tid & 15, r = tid >> 4;
  int wave = tid >> 6, lane = tid & 63;
  const float* rep = P.sumsRep + (size_t)2*RREP*2*HD;
  float aC[8], bC[8];
  #pragma unroll
  for (int k = 0; k < 8; ++k){
    int c = j*8 + k;
    float sS = 0.f, sQ = 0.f;
    for (int rr = 0; rr < RREP; ++rr){
      sS += rep[(size_t)rr*2*HD + c];
      sQ += rep[(size_t)rr*2*HD + HD + c];
    }
    float m = sS*P.invN;
    float var = fmaxf(sQ*P.invN - m*m, 0.f);
    float A = P.g3[c]*rsqrtf(var + EPS);
    aC[k] = A; bC[k] = P.be3[c] - m*A;
  }
  for (int g = bid; g < P.G; g += nblk){
    int start = P.batchPtr[g], end = P.batchPtr[g+1];
    float acc[8] = {};
    for (int i = start + r; i < end; i += 16){
      uint4 q = ((const uint4*)(P.AGG + (size_t)i*HD))[j];
      acc[0] += fmaxf(bflo(q.x)*aC[0] + bC[0], 0.f);
      acc[1] += fmaxf(bfhi(q.x)*aC[1] + bC[1], 0.f);
      acc[2] += fmaxf(bflo(q.y)*aC[2] + bC[2], 0.f);
      acc[3] += fmaxf(bfhi(q.y)*aC[3] + bC[3], 0.f);
      acc[4] += fmaxf(bflo(q.z)*aC[4] + bC[4], 0.f);
      acc[5] += fmaxf(bfhi(q.z)*aC[5] + bC[5], 0.f);
      acc[6] += fmaxf(bflo(q.w)*aC[6] + bC[6], 0.f);
      acc[7] += fmaxf(bfhi(q.w)*aC[7] + bC[7], 0.f);
    }
    #pragma unroll
    for (int k = 0; k < 8; ++k){
      float s = acc[k];
      s += __shfl_xor(s, 16); s += __shfl_xor(s, 32);
      if (lane < 16) S.sm[wave][lane*8 + k] = s;
    }
    __syncthreads();
    if (tid < HD){
      float tot = S.sm[0][tid] + S.sm[1][tid] + S.sm[2][tid] + S.sm[3][tid];
      S.prow[tid] = tot / (float)max(end - start, 1);
    }
    __syncthreads();
    if (tid < FCD){
      float accf = 0.f;
      #pragma unroll 8
      for (int k = 0; k < HD; ++k)
        accf += S.prow[k] * P.fcW1[k*FCD + tid];
      float zv = accf + P.fcb1[tid];
      P.zbuf[(size_t)g*FCD + tid] = zv;
      float* d2 = P.sums2Rep + (size_t)(bid & (R2-1))*(2*FCD);
      atomicAdd(&d2[tid], zv);
      atomicAdd(&d2[FCD + tid], zv*zv);
    }
    __syncthreads();
  }
}

// ---------- phase: BN(fc)+ReLU + fc2 ----------
__device__ __forceinline__ void ph_final(const Params& P, int bid, int nblk){
  int tid = threadIdx.x;
  if (tid < FCD){
    int c = tid;
    float sS = 0.f, sQ = 0.f;
    for (int rr = 0; rr < R2; ++rr){
      sS += P.sums2Rep[(size_t)rr*2*FCD + c];
      sQ += P.sums2Rep[(size_t)rr*2*FCD + FCD + c];
    }
    float m = sS*P.invG;
    float var = fmaxf(sQ*P.invG - m*m, 0.f);
    float A = P.fcg1[c]*rsqrtf(var + EPS);
    float B = P.fcbe1[c] - m*A;
    float w2 = P.fcW2[c];
    for (int g = bid; g < P.G; g += nblk){
      float v = fmaxf(P.zbuf[(size_t)g*FCD + c]*A + B, 0.f) * w2;
      #pragma unroll
      for (int o = 32; o > 0; o >>= 1) v += __shfl_down(v, o, 64);
      if (c == 0) P.out[g] = v + P.fcb2[0];
    }
  }
}

// ================= cooperative mega-kernel: whole pipeline, 1 dispatch =========
__global__ __launch_bounds__(256, 3) void k_mega(Params P){
  __shared__ SMem S;
  cg::grid_group grid = cg::this_grid();
  int bid = blockIdx.x, nblk = gridDim.x;
  int gtid = bid*256 + threadIdx.x, gs = nblk*256;

  ph_zero(P, gtid, gs);
  grid.sync();
  ph_setup(P, S.hist, bid, nblk);
  grid.sync();
  ph_bucket(P, S.bk, bid, nblk);
  grid.sync();
  ph_csr(P, S.cs, bid, nblk);
  grid.sync();
  ph_gemm<0>(P, S.ge, bid, nblk, P.x, P.Wf, nullptr, nullptr, nullptr, P.HWb);
  grid.sync();
  ph_gather(P, S.ga, bid, nblk, P.HWb, P.AGG, P.sumsRep);
  grid.sync();
  ph_gemm<1>(P, S.ge, bid, nblk, P.AGG, P.Wf + 16384, P.sumsRep, P.g1, P.be1, P.HWb);
  grid.sync();
  ph_gather(P, S.ga, bid, nblk, P.HWb, P.AGG, P.sumsRep + (size_t)RREP*2*HD);
  grid.sync();
  ph_gemm<1>(P, S.ge, bid, nblk, P.AGG, P.Wf + 32768, P.sumsRep + (size_t)RREP*2*HD, P.g2, P.be2, P.HWb);
  grid.sync();
  ph_gather(P, S.ga, bid, nblk, P.HWb, P.AGG, P.sumsRep + (size_t)2*RREP*2*HD);
  grid.sync();
  ph_head(P, S.hd, bid, nblk);
  grid.sync();
  ph_final(P, bid, nblk);
}

// ================= fallback wrappers (identical phase code, 12 dispatches) =====
__global__ __launch_bounds__(256) void kf_zero(Params P){
  ph_zero(P, blockIdx.x*256 + threadIdx.x, gridDim.x*256);
}
__global__ __launch_bounds__(256) void kf_setup(Params P){
  __shared__ SmHist S; ph_setup(P, S, blockIdx.x, gridDim.x);
}
__global__ __launch_bounds__(256) void kf_bucket(Params P){
  __shared__ SmBucket S; ph_bucket(P, S, blockIdx.x, gridDim.x);
}
__global__ __launch_bounds__(256) void kf_csr(Params P){
  __shared__ SmCsr S; ph_csr(P, S, blockIdx.x, gridDim.x);
}
__global__ __launch_bounds__(256) void kf_gemm0(Params P){
  __shared__ SmGemm S;
  ph_gemm<0>(P, S, blockIdx.x, gridDim.x, P.x, P.Wf, nullptr, nullptr, nullptr, P.HWb);
}
__global__ __launch_bounds__(256) void kf_gemm1(Params P, int layer){
  __shared__ SmGemm S;
  const float* rep = P.sumsRep + (size_t)(layer-1)*RREP*2*HD;
  const float* g  = (layer == 1) ? P.g1  : P.g2;
  const float* be = (layer == 1) ? P.be1 : P.be2;
  ph_gemm<1>(P, S, blockIdx.x, gridDim.x, P.AGG, P.Wf + layer*16384, rep, g, be, P.HWb);
}
__global__ __launch_bounds__(256) void kf_gather(Params P, int layer){
  __shared__ SmGather S;
  ph_gather(P, S, blockIdx.x, gridDim.x, P.HWb, P.AGG, P.sumsRep + (size_t)layer*RREP*2*HD);
}
__global__ __launch_bounds__(256) void kf_head(Params P){
  __shared__ SmHead S; ph_head(P, S, blockIdx.x, gridDim.x);
}
__global__ __launch_bounds__(256) void kf_final(Params P){
  ph_final(P, blockIdx.x, gridDim.x);
}

// ------------------- launch -------------------
extern "C" void kernel_launch(void* const* d_in, const int* in_sizes, int n_in,
                              void* d_out, int out_size, void* d_ws, size_t ws_size,
                              hipStream_t stream){
  Params P;
  P.x    = (const float*)d_in[0];
  const int* ei = (const int*)d_in[1];
  P.batch= (const int*)d_in[2];
  P.W1 = (const float*)d_in[3];  P.g1 = (const float*)d_in[5];  P.be1 = (const float*)d_in[6];
  P.W2 = (const float*)d_in[7];  P.g2 = (const float*)d_in[9];  P.be2 = (const float*)d_in[10];
  P.W3 = (const float*)d_in[11]; P.g3 = (const float*)d_in[13]; P.be3 = (const float*)d_in[14];
  P.fcW1 = (const float*)d_in[15]; P.fcb1 = (const float*)d_in[16];
  P.fcg1 = (const float*)d_in[17]; P.fcbe1 = (const float*)d_in[18];
  P.fcW2 = (const float*)d_in[19]; P.fcb2 = (const float*)d_in[20];
  P.out = (float*)d_out;

  P.N = in_sizes[0] / HD;
  P.E = in_sizes[1] / 2;
  P.G = out_size;
  P.esrc = ei; P.edst = ei + P.E;
  P.nEB = (P.E + 4095)/4096;
  P.NB  = (P.N + 255)/256;
  P.invN = 1.0f/(float)P.N; P.invG = 1.0f/(float)P.G;

  char* p = (char*)d_ws;
  auto alloc = [&](size_t bytes)->void*{
    void* r = (void*)p; p += (bytes + 255) & ~(size_t)255; return r;
  };
  int ZW = 512 + 3*RREP*2*HD + R2*2*FCD;
  P.zeroBase = (int*)alloc((size_t)ZW*4);
  P.zeroWords = ZW;
  P.bucketHist   = P.zeroBase;
  P.bucketCursor = P.zeroBase + 256;
  P.sumsRep  = (float*)(P.zeroBase + 512);
  P.sums2Rep = (float*)(P.zeroBase + 512 + 3*RREP*2*HD);
  P.batchPtr = (int*)  alloc((size_t)(P.G+1)*4);
  P.tmp      = (int2*) alloc((size_t)P.E*8);
  P.rowptr   = (int*)  alloc((size_t)(P.N+1)*4);
  P.csrc     = (int*)  alloc((size_t)P.E*4);
  P.dis      = (float*)alloc((size_t)P.N*4);
  P.HWb      = (ushort*)alloc((size_t)P.N*HD*2);
  P.AGG      = (ushort*)alloc((size_t)P.N*HD*2);
  P.Wf       = (ushort*)alloc((size_t)3*HD*HD*2);
  P.zbuf     = (float*)alloc((size_t)P.G*FCD*4);

  // cooperative grid size: computed once from actual occupancy (LDS union 42KB
  // + launch_bounds(256,3) -> expect 3 blocks/CU -> 768 blocks on 256 CUs)
  static int coopGrid = -2;
  if (coopGrid == -2){
    int nb = 0;
    hipError_t e1 = hipOccupancyMaxActiveBlocksPerMultiprocessor(
        &nb, reinterpret_cast<const void*>(&k_mega), 256, 0);
    int cus = 256;
    hipDeviceProp_t prop;
    int dev = 0;
    if (hipGetDevice(&dev) == hipSuccess &&
        hipGetDeviceProperties(&prop, dev) == hipSuccess &&
        prop.multiProcessorCount > 0)
      cus = prop.multiProcessorCount;
    coopGrid = (e1 == hipSuccess && nb > 0) ? nb*cus : 0;
    if (coopGrid > 2048) coopGrid = 2048;
  }

  bool ok = false;
  if (coopGrid >= 64){
    Params Pl = P;
    void* args[] = { (void*)&Pl };
    ok = (hipLaunchCooperativeKernel(reinterpret_cast<const void*>(&k_mega),
                                     dim3(coopGrid), dim3(256), args, 0, stream)
          == hipSuccess);
  }
  if (!ok){
    int gB = (P.N + 63)/64, aB = (P.N + 15)/16;
    kf_zero  <<<64,     256, 0, stream>>>(P);
    kf_setup <<<256,    256, 0, stream>>>(P);
    kf_bucket<<<P.nEB,  256, 0, stream>>>(P);
    kf_csr   <<<P.NB,   256, 0, stream>>>(P);
    kf_gemm0 <<<gB,     256, 0, stream>>>(P);
    kf_gather<<<aB,     256, 0, stream>>>(P, 0);
    kf_gemm1 <<<gB,     256, 0, stream>>>(P, 1);
    kf_gather<<<aB,     256, 0, stream>>>(P, 1);
    kf_gemm1 <<<gB,     256, 0, stream>>>(P, 2);
    kf_gather<<<aB,     256, 0, stream>>>(P, 2);
    kf_head  <<<P.G,    256, 0, stream>>>(P);
    kf_final <<<P.G,    256, 0, stream>>>(P);
  }
}

// Round 3
// 419.534 us; speedup vs baseline: 2.0283x; 2.0283x over previous
//
#include <hip/hip_runtime.h>

#define EPS 1e-5f
constexpr int HD = 128;   // node feature / hidden dim
constexpr int FCD = 64;   // fc hidden dim
constexpr int RREP = 32;  // BN-stat atomic replicas (contention / 32)
constexpr int R2 = 8;     // fc-stat atomic replicas

typedef __attribute__((ext_vector_type(8))) short short8;
typedef __attribute__((ext_vector_type(4))) float floatx4;

// ---------- bf16 helpers ----------
__device__ inline ushort f2bf(float f){
  union{float f; unsigned u;} v; v.f = f;
  unsigned r = v.u + 0x7FFFu + ((v.u >> 16) & 1u);
  return (ushort)(r >> 16);
}
__device__ inline float bflo(unsigned u){ union{unsigned i; float f;} v; v.i = u << 16;        return v.f; }
__device__ inline float bfhi(unsigned u){ union{unsigned i; float f;} v; v.i = u & 0xFFFF0000u; return v.f; }
__device__ inline float bf2f(ushort u){ union{unsigned i; float f;} v; v.i = ((unsigned)u) << 16; return v.f; }

// ================= fused setup: edge histogram + batch rowptr + W pack ==========
__global__ __launch_bounds__(256) void k_setup(const int* __restrict__ dst,
                                               int* __restrict__ bucketHist, int E, int nEB,
                                               const int* __restrict__ batch,
                                               int* __restrict__ batchPtr, int N, int G, int nBB,
                                               const float* __restrict__ W1,
                                               const float* __restrict__ W2,
                                               const float* __restrict__ W3,
                                               ushort* __restrict__ Wf){
  __shared__ int h[256];
  int t = threadIdx.x;
  int b = blockIdx.x;
  if (b < nEB){
    h[t] = 0;
    __syncthreads();
    int base = b*4096;
    #pragma unroll
    for (int k = 0; k < 16; ++k){
      int e = base + k*256 + t;
      if (e < E) atomicAdd(&h[dst[e] >> 8], 1);
    }
    __syncthreads();
    if (h[t]) atomicAdd(&bucketHist[t], h[t]);
  } else if (b < nEB + nBB){
    int i = (b - nEB)*256 + t;
    if (i < N){
      int bb = batch[i];
      int prev = (i == 0) ? -1 : batch[i-1];
      for (int g = prev + 1; g <= bb; ++g) batchPtr[g] = i;
      if (i == N-1)
        for (int g = bb + 1; g <= G; ++g) batchPtr[g] = N;
    }
  } else {
    int idx4 = b - nEB - nBB;            // 0..191
    int l = idx4 >> 6;
    int idx = (idx4 & 63)*256 + t;       // 0..16383
    const float* Ws = (l == 0) ? W1 : (l == 1) ? W2 : W3;
    int k = idx >> 7, n = idx & 127;
    float w = Ws[idx];
    int kb = k >> 5, q = (k >> 3) & 3, jj = k & 7;
    int nt = n >> 4, col = n & 15;
    Wf[(size_t)l*16384 + (((size_t)(kb*8 + nt)*64 + q*16 + col)*8 + jj)] = f2bf(w);
  }
}

// redundant per-block exclusive scan of the 256-entry bucket histogram
__device__ __forceinline__ void scan_hist(const int* __restrict__ hist,
                                          int* baseArr, int* wt){
  int t = threadIdx.x, lane = t & 63, w = t >> 6;
  int v = hist[t];
  int incl = v;
  #pragma unroll
  for (int o = 1; o < 64; o <<= 1){
    int x = __shfl_up(incl, o, 64);
    if (lane >= o) incl += x;
  }
  if (lane == 63) wt[w] = incl;
  __syncthreads();
  int woff = 0;
  for (int i = 0; i < w; ++i) woff += wt[i];
  baseArr[t] = woff + incl - v;
  __syncthreads();
}

// LDS-staged bucket scatter (base computed in-block; cursor is relative)
__global__ __launch_bounds__(256) void k_bucket(const int* __restrict__ src,
                                                const int* __restrict__ dst,
                                                const int* __restrict__ bucketHist,
                                                int* __restrict__ bucketCursor,
                                                int2* __restrict__ tmp, int E){
  __shared__ int h[256], ls[256], cur[256], gb[256], baseArr[256];
  __shared__ int wt[4];
  __shared__ int2 staged[4096];
  __shared__ unsigned char bos[4096];
  int t = threadIdx.x, lane = t & 63, w = t >> 6;
  scan_hist(bucketHist, baseArr, wt);
  int base = blockIdx.x*4096;
  int2 ed[16]; int bk[16];
  h[t] = 0;
  __syncthreads();
  #pragma unroll
  for (int k = 0; k < 16; ++k){
    int e = base + k*256 + t;
    if (e < E){
      int s = src[e], d = dst[e];
      ed[k] = make_int2(s, d);
      bk[k] = d >> 8;
      atomicAdd(&h[bk[k]], 1);
    } else bk[k] = -1;
  }
  __syncthreads();
  int v = h[t];
  int incl = v;
  #pragma unroll
  for (int o = 1; o < 64; o <<= 1){
    int x = __shfl_up(incl, o, 64);
    if (lane >= o) incl += x;
  }
  if (lane == 63) wt[w] = incl;
  __syncthreads();
  int woff = 0;
  for (int i = 0; i < w; ++i) woff += wt[i];
  ls[t] = woff + incl - v;
  cur[t] = ls[t];
  if (v > 0) gb[t] = baseArr[t] + atomicAdd(&bucketCursor[t], v);
  __syncthreads();
  #pragma unroll
  for (int k = 0; k < 16; ++k){
    if (bk[k] >= 0){
      int lp = atomicAdd(&cur[bk[k]], 1);
      staged[lp] = ed[k];
      bos[lp] = (unsigned char)bk[k];
    }
  }
  __syncthreads();
  int nvalid = min(4096, E - base);
  #pragma unroll
  for (int k = 0; k < 16; ++k){
    int i = k*256 + t;
    if (i < nvalid){
      int b = bos[i];
      tmp[gb[b] + (i - ls[b])] = staged[i];
    }
  }
}

// one block per bucket: group by exact dst, emit rowptr/dis/csrc
__global__ __launch_bounds__(256) void k_csr(const int2* __restrict__ tmp,
                                             const int* __restrict__ bucketHist,
                                             int* __restrict__ rowptr,
                                             float* __restrict__ dis,
                                             int* __restrict__ csrc, int N){
  __shared__ int h[256], ls[256], cur[256], baseArr[256];
  __shared__ int wt[4];
  __shared__ int stagedSrc[6144];            // cap >> max bucket size (~4350)
  int b = blockIdx.x, t = threadIdx.x, lane = t & 63, w = t >> 6;
  scan_hist(bucketHist, baseArr, wt);
  int ebase = baseArr[b];
  int cnt = bucketHist[b];
  int node0 = b << 8;
  h[t] = 0;
  __syncthreads();
  for (int i = t; i < cnt; i += 256){
    int2 e = tmp[ebase + i];
    atomicAdd(&h[e.y - node0], 1);
  }
  __syncthreads();
  int v = h[t];
  int incl = v;
  #pragma unroll
  for (int o = 1; o < 64; o <<= 1){
    int x = __shfl_up(incl, o, 64);
    if (lane >= o) incl += x;
  }
  if (lane == 63) wt[w] = incl;
  __syncthreads();
  int woff = 0;
  for (int i = 0; i < w; ++i) woff += wt[i];
  int ex = woff + incl - v;
  ls[t] = ex; cur[t] = ex;
  int d = node0 + t;
  if (d < N){
    rowptr[d+1] = ebase + ex + v;
    dis[d] = rsqrtf((float)v + 1.0f);
  }
  if (b == 0 && t == 0) rowptr[0] = 0;
  __syncthreads();
  for (int i = t; i < cnt; i += 256){
    int2 e = tmp[ebase + i];
    int lp = atomicAdd(&cur[e.y - node0], 1);
    stagedSrc[lp] = e.x;
  }
  __syncthreads();
  for (int i = t; i < cnt; i += 256)
    csrc[ebase + i] = stagedSrc[i];
}

// ------------------- GEMM: bf16 MFMA, fused BN-affine+ReLU on A, dis-scale on out ----
// MODE 0: A fp32 (= x), plain convert. MODE 1: A bf16 (= AGG), affine+relu in fp32.
template<int MODE>
__global__ __launch_bounds__(256) void k_gemm(const void* __restrict__ Av,
                                              const ushort* __restrict__ Wf,
                                              const float* __restrict__ rep,
                                              const float* __restrict__ g,
                                              const float* __restrict__ be,
                                              const float* __restrict__ dis,
                                              ushort* __restrict__ O, int n, float invN){
  __shared__ float aL[HD], bL[HD];
  int tid = threadIdx.x;
  if (MODE){
    if (tid < HD){
      float sS = 0.f, sQ = 0.f;
      #pragma unroll 4
      for (int r = 0; r < RREP; ++r){
        sS += rep[(size_t)r*2*HD + tid];
        sQ += rep[(size_t)r*2*HD + HD + tid];
      }
      float m = sS*invN;
      float var = fmaxf(sQ*invN - m*m, 0.f);
      float Ac = g[tid]*rsqrtf(var + EPS);
      aL[tid] = Ac; bL[tid] = be[tid] - m*Ac;
    }
    __syncthreads();
  }
  int lane = tid & 63, wave = tid >> 6;
  int quad = lane >> 4, r16 = lane & 15;
  int row = blockIdx.x*64 + wave*16 + r16;
  int rowc = min(row, n-1);
  floatx4 acc[8] = {};
  #pragma unroll
  for (int kb = 0; kb < 4; ++kb){
    int k0 = kb*32 + quad*8;
    short8 af;
    if (MODE){
      const ushort* Arow = (const ushort*)Av + (size_t)rowc*HD;
      short8 raw = *(const short8*)(Arow + k0);
      #pragma unroll
      for (int jj = 0; jj < 8; ++jj){
        float f = bf2f((ushort)raw[jj]);
        f = fmaxf(f*aL[k0+jj] + bL[k0+jj], 0.f);
        af[jj] = (short)f2bf(f);
      }
    } else {
      const float* Arow = (const float*)Av + (size_t)rowc*HD;
      float4 x0 = *(const float4*)(Arow + k0);
      float4 x1 = *(const float4*)(Arow + k0 + 4);
      af[0] = (short)f2bf(x0.x); af[1] = (short)f2bf(x0.y);
      af[2] = (short)f2bf(x0.z); af[3] = (short)f2bf(x0.w);
      af[4] = (short)f2bf(x1.x); af[5] = (short)f2bf(x1.y);
      af[6] = (short)f2bf(x1.z); af[7] = (short)f2bf(x1.w);
    }
    const ushort* wp = Wf + ((size_t)(kb*8)*64 + lane)*8;
    #pragma unroll
    for (int nt = 0; nt < 8; ++nt){
      short8 bf = *(const short8*)(wp + (size_t)nt*64*8);
      acc[nt] = __builtin_amdgcn_mfma_f32_16x16x32_bf16(af, bf, acc[nt], 0, 0, 0);
    }
  }
  int rbase = blockIdx.x*64 + wave*16 + quad*4;
  float ds[4];
  #pragma unroll
  for (int r = 0; r < 4; ++r) ds[r] = dis[min(rbase + r, n-1)];
  #pragma unroll
  for (int nt = 0; nt < 8; ++nt){
    #pragma unroll
    for (int r = 0; r < 4; ++r){
      int rr = rbase + r;
      if (rr < n) O[(size_t)rr*HD + nt*16 + r16] = f2bf(acc[nt][r]*ds[r]);
    }
  }
}

// ------------------- edge aggregation + BN stats (replicated atomics) -------------
__global__ __launch_bounds__(256) void k_gather(const ushort* __restrict__ hw,
                                                const int* __restrict__ rowptr,
                                                const int* __restrict__ csrc,
                                                const float* __restrict__ dis,
                                                ushort* __restrict__ agg,
                                                float* __restrict__ repOut, int N){
  __shared__ float2 sm[4][HD];
  int grp = threadIdx.x >> 4, j = threadIdx.x & 15;
  int wave = threadIdx.x >> 6, lane = threadIdx.x & 63;
  int i = blockIdx.x*16 + grp;
  bool valid = (i < N);
  int ic = valid ? i : N-1;
  uint4 q = ((const uint4*)(hw + (size_t)ic*HD))[j];
  float a[8];
  a[0] = bflo(q.x); a[1] = bfhi(q.x);
  a[2] = bflo(q.y); a[3] = bfhi(q.y);
  a[4] = bflo(q.z); a[5] = bfhi(q.z);
  a[6] = bflo(q.w); a[7] = bfhi(q.w);
  int e = rowptr[ic], e1 = rowptr[ic+1];
  #define ADD8(Q) \
    a[0] += bflo(Q.x); a[1] += bfhi(Q.x); \
    a[2] += bflo(Q.y); a[3] += bfhi(Q.y); \
    a[4] += bflo(Q.z); a[5] += bfhi(Q.z); \
    a[6] += bflo(Q.w); a[7] += bfhi(Q.w);
  while (e < e1 && (e & 3)){
    uint4 qq = ((const uint4*)(hw + (size_t)csrc[e]*HD))[j];
    ADD8(qq);
    e++;
  }
  int4 c0, c1;
  if (e + 8 <= e1){
    c0 = *(const int4*)&csrc[e];
    c1 = *(const int4*)&csrc[e+4];
  }
  while (e + 8 <= e1){
    int en = e + 8;
    int4 n0, n1;
    if (en + 8 <= e1){
      n0 = *(const int4*)&csrc[en];
      n1 = *(const int4*)&csrc[en+4];
    }
    uint4 q0 = ((const uint4*)(hw + (size_t)c0.x*HD))[j];
    uint4 q1 = ((const uint4*)(hw + (size_t)c0.y*HD))[j];
    uint4 q2 = ((const uint4*)(hw + (size_t)c0.z*HD))[j];
    uint4 q3 = ((const uint4*)(hw + (size_t)c0.w*HD))[j];
    uint4 q4 = ((const uint4*)(hw + (size_t)c1.x*HD))[j];
    uint4 q5 = ((const uint4*)(hw + (size_t)c1.y*HD))[j];
    uint4 q6 = ((const uint4*)(hw + (size_t)c1.z*HD))[j];
    uint4 q7 = ((const uint4*)(hw + (size_t)c1.w*HD))[j];
    ADD8(q0); ADD8(q1); ADD8(q2); ADD8(q3);
    ADD8(q4); ADD8(q5); ADD8(q6); ADD8(q7);
    c0 = n0; c1 = n1; e = en;
  }
  if (e + 4 <= e1){
    int4 tt = *(const int4*)&csrc[e];
    uint4 q0 = ((const uint4*)(hw + (size_t)tt.x*HD))[j];
    uint4 q1 = ((const uint4*)(hw + (size_t)tt.y*HD))[j];
    uint4 q2 = ((const uint4*)(hw + (size_t)tt.z*HD))[j];
    uint4 q3 = ((const uint4*)(hw + (size_t)tt.w*HD))[j];
    ADD8(q0); ADD8(q1); ADD8(q2); ADD8(q3);
    e += 4;
  }
  for (; e < e1; ++e){
    uint4 qq = ((const uint4*)(hw + (size_t)csrc[e]*HD))[j];
    ADD8(qq);
  }
  #undef ADD8
  float sc = dis[ic];
  #pragma unroll
  for (int k = 0; k < 8; ++k) a[k] *= sc;
  if (valid){
    uint4 o;
    o.x = (unsigned)f2bf(a[0]) | ((unsigned)f2bf(a[1]) << 16);
    o.y = (unsigned)f2bf(a[2]) | ((unsigned)f2bf(a[3]) << 16);
    o.z = (unsigned)f2bf(a[4]) | ((unsigned)f2bf(a[5]) << 16);
    o.w = (unsigned)f2bf(a[6]) | ((unsigned)f2bf(a[7]) << 16);
    ((uint4*)(agg + (size_t)i*HD))[j] = o;
  }
  float z = valid ? 1.f : 0.f;
  #pragma unroll
  for (int k = 0; k < 8; ++k){
    float s = a[k]*z, qq = a[k]*a[k]*z;
    s  += __shfl_xor(s, 16);  s  += __shfl_xor(s, 32);
    qq += __shfl_xor(qq, 16); qq += __shfl_xor(qq, 32);
    if (lane < 16) sm[wave][lane*8 + k] = make_float2(s, qq);
  }
  __syncthreads();
  int t = threadIdx.x;
  if (t < HD){
    float2 r0 = sm[0][t], r1 = sm[1][t], r2 = sm[2][t], r3 = sm[3][t];
    float* d = repOut + (size_t)(blockIdx.x & (RREP-1))*(2*HD);
    atomicAdd(&d[t],      r0.x + r1.x + r2.x + r3.x);
    atomicAdd(&d[HD + t], r0.y + r1.y + r2.y + r3.y);
  }
}

// ------------------- head: per-graph mean pool (BN3+ReLU) + fc1 + z-stats ---------
__global__ __launch_bounds__(256) void k_head(const ushort* __restrict__ h,
                                              const int* __restrict__ batchPtr,
                                              const float* __restrict__ rep,
                                              const float* __restrict__ gw,
                                              const float* __restrict__ be,
                                              const float* __restrict__ fcW1,
                                              const float* __restrict__ fcb1,
                                              float* __restrict__ zbuf,
                                              float* __restrict__ sums2Rep, float invN){
  __shared__ float sm[4][HD];
  __shared__ float prow[HD];
  int g = blockIdx.x;
  int start = batchPtr[g], end = batchPtr[g+1];
  int tid = threadIdx.x;
  int j = tid & 15, r = tid >> 4;
  int wave = tid >> 6, lane = tid & 63;
  float aC[8], bC[8];
  #pragma unroll
  for (int k = 0; k < 8; ++k){
    int c = j*8 + k;
    float sS = 0.f, sQ = 0.f;
    #pragma unroll 4
    for (int rr = 0; rr < RREP; ++rr){
      sS += rep[(size_t)rr*2*HD + c];
      sQ += rep[(size_t)rr*2*HD + HD + c];
    }
    float m = sS*invN;
    float var = fmaxf(sQ*invN - m*m, 0.f);
    float A = gw[c]*rsqrtf(var + EPS);
    aC[k] = A; bC[k] = be[c] - m*A;
  }
  float acc[8] = {};
  for (int i = start + r; i < end; i += 16){
    uint4 q = ((const uint4*)(h + (size_t)i*HD))[j];
    acc[0] += fmaxf(bflo(q.x)*aC[0] + bC[0], 0.f);
    acc[1] += fmaxf(bfhi(q.x)*aC[1] + bC[1], 0.f);
    acc[2] += fmaxf(bflo(q.y)*aC[2] + bC[2], 0.f);
    acc[3] += fmaxf(bfhi(q.y)*aC[3] + bC[3], 0.f);
    acc[4] += fmaxf(bflo(q.z)*aC[4] + bC[4], 0.f);
    acc[5] += fmaxf(bfhi(q.z)*aC[5] + bC[5], 0.f);
    acc[6] += fmaxf(bflo(q.w)*aC[6] + bC[6], 0.f);
    acc[7] += fmaxf(bfhi(q.w)*aC[7] + bC[7], 0.f);
  }
  #pragma unroll
  for (int k = 0; k < 8; ++k){
    float s = acc[k];
    s += __shfl_xor(s, 16); s += __shfl_xor(s, 32);
    if (lane < 16) sm[wave][lane*8 + k] = s;
  }
  __syncthreads();
  if (tid < HD){
    float tot = sm[0][tid] + sm[1][tid] + sm[2][tid] + sm[3][tid];
    prow[tid] = tot / (float)max(end - start, 1);
  }
  __syncthreads();
  if (tid < FCD){
    float accf = 0.f;
    #pragma unroll 8
    for (int k = 0; k < HD; ++k)
      accf += prow[k] * fcW1[k*FCD + tid];
    float zv = accf + fcb1[tid];
    zbuf[(size_t)g*FCD + tid] = zv;
    float* d2 = sums2Rep + (size_t)(g & (R2-1))*(2*FCD);
    atomicAdd(&d2[tid], zv);
    atomicAdd(&d2[FCD + tid], zv*zv);
  }
}

__global__ __launch_bounds__(64) void k_final(const float* __restrict__ z,
                                              const float* __restrict__ sums2Rep,
                                              const float* __restrict__ g,
                                              const float* __restrict__ be,
                                              const float* __restrict__ w2,
                                              const float* __restrict__ b2,
                                              float* __restrict__ out, int G, float invG){
  int gg = blockIdx.x, c = threadIdx.x;
  float sS = 0.f, sQ = 0.f;
  #pragma unroll
  for (int rr = 0; rr < R2; ++rr){
    sS += sums2Rep[(size_t)rr*2*FCD + c];
    sQ += sums2Rep[(size_t)rr*2*FCD + FCD + c];
  }
  float m = sS*invG;
  float var = fmaxf(sQ*invG - m*m, 0.f);
  float A = g[c]*rsqrtf(var + EPS);
  float B = be[c] - m*A;
  float v = fmaxf(z[(size_t)gg*FCD + c]*A + B, 0.f) * w2[c];
  #pragma unroll
  for (int o = 32; o > 0; o >>= 1) v += __shfl_down(v, o, 64);
  if (c == 0) out[gg] = v + b2[0];
}

// ------------------- launch -------------------

extern "C" void kernel_launch(void* const* d_in, const int* in_sizes, int n_in,
                              void* d_out, int out_size, void* d_ws, size_t ws_size,
                              hipStream_t stream){
  const float* x    = (const float*)d_in[0];
  const int*   ei   = (const int*)d_in[1];
  const int*   batch= (const int*)d_in[2];
  const float* W1 = (const float*)d_in[3];
  const float* g1 = (const float*)d_in[5];
  const float* be1= (const float*)d_in[6];
  const float* W2 = (const float*)d_in[7];
  const float* g2 = (const float*)d_in[9];
  const float* be2= (const float*)d_in[10];
  const float* W3 = (const float*)d_in[11];
  const float* g3 = (const float*)d_in[13];
  const float* be3= (const float*)d_in[14];
  const float* fcW1 = (const float*)d_in[15];
  const float* fcb1 = (const float*)d_in[16];
  const float* fcg1 = (const float*)d_in[17];
  const float* fcbe1= (const float*)d_in[18];
  const float* fcW2 = (const float*)d_in[19];
  const float* fcb2 = (const float*)d_in[20];
  float* out = (float*)d_out;

  const int N = in_sizes[0] / HD;      // 50000
  const int E = in_sizes[1] / 2;       // 800000
  const int G = out_size;              // 500

  const int* esrc = ei;
  const int* edst = ei + E;

  char* p = (char*)d_ws;
  auto alloc = [&](size_t bytes)->void*{
    void* r = (void*)p; p += (bytes + 255) & ~(size_t)255; return r;
  };
  int gatherBlocks = (N + 15)/16;
  int nEB = (E + 4095)/4096;           // 196 edge blocks
  int nBB = (N + 255)/256;             // 196 batch-ptr blocks
  int NB  = (N + 255)/256;             // 196 node buckets (<=256 required)

  // zeroed region: bucketHist | bucketCursor | sumsRep[3][RREP][2*HD] | sums2Rep[R2][2*FCD]
  int ZW = 512 + 3*RREP*2*HD + R2*2*FCD;
  int*    zeroBase = (int*) alloc((size_t)ZW*4);
  int*    bucketHist   = zeroBase;
  int*    bucketCursor = zeroBase + 256;
  float*  sumsRep  = (float*)(zeroBase + 512);
  float*  sums2Rep = sumsRep + 3*RREP*2*HD;
  int*    batchPtr = (int*) alloc((size_t)(G+1)*4);
  int2*   tmp    = (int2*)  alloc((size_t)E*8);
  int*    rowptr = (int*)   alloc((size_t)(N+1)*4);
  int*    csrc   = (int*)   alloc((size_t)E*4);
  float*  dis    = (float*) alloc((size_t)N*4);
  ushort* HWb    = (ushort*)alloc((size_t)N*HD*2);
  ushort* AGG    = (ushort*)alloc((size_t)N*HD*2);
  ushort* Wf     = (ushort*)alloc((size_t)3*HD*HD*2);
  float*  zbuf   = (float*) alloc((size_t)G*FCD*4);

  float invN = 1.0f/(float)N, invG = 1.0f/(float)G;

  hipMemsetAsync(zeroBase, 0, (size_t)ZW*4, stream);
  k_setup <<<nEB + nBB + 3*(HD*HD/256), 256, 0, stream>>>(
      edst, bucketHist, E, nEB, batch, batchPtr, N, G, nBB, W1, W2, W3, Wf);
  k_bucket<<<nEB, 256, 0, stream>>>(esrc, edst, bucketHist, bucketCursor, tmp, E);
  k_csr   <<<NB, 256, 0, stream>>>(tmp, bucketHist, rowptr, dis, csrc, N);

  int gemmBlocks = (N + 63)/64;

  // layer 1
  k_gemm<0> <<<gemmBlocks, 256, 0, stream>>>(x,   Wf,         nullptr, nullptr, nullptr, dis, HWb, N, invN);
  k_gather  <<<gatherBlocks, 256, 0, stream>>>(HWb, rowptr, csrc, dis, AGG, sumsRep, N);
  // layer 2 (BN1+ReLU fused into A-load)
  k_gemm<1> <<<gemmBlocks, 256, 0, stream>>>(AGG, Wf + 16384, sumsRep, g1, be1, dis, HWb, N, invN);
  k_gather  <<<gatherBlocks, 256, 0, stream>>>(HWb, rowptr, csrc, dis, AGG, sumsRep + (size_t)RREP*2*HD, N);
  // layer 3 (BN2+ReLU fused into A-load)
  k_gemm<1> <<<gemmBlocks, 256, 0, stream>>>(AGG, Wf + 32768, sumsRep + (size_t)RREP*2*HD, g2, be2, dis, HWb, N, invN);
  k_gather  <<<gatherBlocks, 256, 0, stream>>>(HWb, rowptr, csrc, dis, AGG, sumsRep + (size_t)2*RREP*2*HD, N);

  // head: pool(BN3+ReLU) + fc1 + stats, then BN+fc2
  k_head  <<<G, 256, 0, stream>>>(AGG, batchPtr, sumsRep + (size_t)2*RREP*2*HD, g3, be3,
                                  fcW1, fcb1, zbuf, sums2Rep, invN);
  k_final <<<G, FCD, 0, stream>>>(zbuf, sums2Rep, fcg1, fcbe1, fcW2, fcb2, out, G, invG);
}

// Round 4
// 307.814 us; speedup vs baseline: 2.7644x; 1.3629x over previous
//
#include <hip/hip_runtime.h>

#define EPS 1e-5f
constexpr int HD = 128;   // node feature / hidden dim
constexpr int FCD = 64;   // fc hidden dim
constexpr int RREP = 32;  // BN-stat atomic replicas (contention / 32)
constexpr int R2 = 8;     // fc-stat atomic replicas

typedef __attribute__((ext_vector_type(8))) short short8;
typedef __attribute__((ext_vector_type(4))) float floatx4;

// ---------- bf16 helpers ----------
__device__ inline ushort f2bf(float f){
  union{float f; unsigned u;} v; v.f = f;
  unsigned r = v.u + 0x7FFFu + ((v.u >> 16) & 1u);
  return (ushort)(r >> 16);
}
__device__ inline float bflo(unsigned u){ union{unsigned i; float f;} v; v.i = u << 16;        return v.f; }
__device__ inline float bfhi(unsigned u){ union{unsigned i; float f;} v; v.i = u & 0xFFFF0000u; return v.f; }
__device__ inline float bf2f(ushort u){ union{unsigned i; float f;} v; v.i = ((unsigned)u) << 16; return v.f; }

// ================= fused setup: edge histogram + batch rowptr + W pack ==========
__global__ __launch_bounds__(256) void k_setup(const int* __restrict__ dst,
                                               int* __restrict__ bucketHist, int E, int nEB,
                                               const int* __restrict__ batch,
                                               int* __restrict__ batchPtr, int N, int G, int nBB,
                                               const float* __restrict__ W1,
                                               const float* __restrict__ W2,
                                               const float* __restrict__ W3,
                                               ushort* __restrict__ Wf){
  __shared__ int h[256];
  int t = threadIdx.x;
  int b = blockIdx.x;
  if (b < nEB){
    h[t] = 0;
    __syncthreads();
    int base = b*4096;
    #pragma unroll
    for (int k = 0; k < 16; ++k){
      int e = base + k*256 + t;
      if (e < E) atomicAdd(&h[dst[e] >> 8], 1);
    }
    __syncthreads();
    if (h[t]) atomicAdd(&bucketHist[t], h[t]);
  } else if (b < nEB + nBB){
    int i = (b - nEB)*256 + t;
    if (i < N){
      int bb = batch[i];
      int prev = (i == 0) ? -1 : batch[i-1];
      for (int g = prev + 1; g <= bb; ++g) batchPtr[g] = i;
      if (i == N-1)
        for (int g = bb + 1; g <= G; ++g) batchPtr[g] = N;
    }
  } else {
    int idx4 = b - nEB - nBB;            // 0..191
    int l = idx4 >> 6;
    int idx = (idx4 & 63)*256 + t;       // 0..16383
    const float* Ws = (l == 0) ? W1 : (l == 1) ? W2 : W3;
    int k = idx >> 7, n = idx & 127;
    float w = Ws[idx];
    int kb = k >> 5, q = (k >> 3) & 3, jj = k & 7;
    int nt = n >> 4, col = n & 15;
    Wf[(size_t)l*16384 + (((size_t)(kb*8 + nt)*64 + q*16 + col)*8 + jj)] = f2bf(w);
  }
}

// redundant per-block exclusive scan of the 256-entry bucket histogram
__device__ __forceinline__ void scan_hist(const int* __restrict__ hist,
                                          int* baseArr, int* wt){
  int t = threadIdx.x, lane = t & 63, w = t >> 6;
  int v = hist[t];
  int incl = v;
  #pragma unroll
  for (int o = 1; o < 64; o <<= 1){
    int x = __shfl_up(incl, o, 64);
    if (lane >= o) incl += x;
  }
  if (lane == 63) wt[w] = incl;
  __syncthreads();
  int woff = 0;
  for (int i = 0; i < w; ++i) woff += wt[i];
  baseArr[t] = woff + incl - v;
  __syncthreads();
}

// LDS-staged bucket scatter (base computed in-block; cursor is relative)
__global__ __launch_bounds__(256) void k_bucket(const int* __restrict__ src,
                                                const int* __restrict__ dst,
                                                const int* __restrict__ bucketHist,
                                                int* __restrict__ bucketCursor,
                                                int2* __restrict__ tmp, int E){
  __shared__ int h[256], ls[256], cur[256], gb[256], baseArr[256];
  __shared__ int wt[4];
  __shared__ int2 staged[4096];
  __shared__ unsigned char bos[4096];
  int t = threadIdx.x, lane = t & 63, w = t >> 6;
  scan_hist(bucketHist, baseArr, wt);
  int base = blockIdx.x*4096;
  int2 ed[16]; int bk[16];
  h[t] = 0;
  __syncthreads();
  #pragma unroll
  for (int k = 0; k < 16; ++k){
    int e = base + k*256 + t;
    if (e < E){
      int s = src[e], d = dst[e];
      ed[k] = make_int2(s, d);
      bk[k] = d >> 8;
      atomicAdd(&h[bk[k]], 1);
    } else bk[k] = -1;
  }
  __syncthreads();
  int v = h[t];
  int incl = v;
  #pragma unroll
  for (int o = 1; o < 64; o <<= 1){
    int x = __shfl_up(incl, o, 64);
    if (lane >= o) incl += x;
  }
  if (lane == 63) wt[w] = incl;
  __syncthreads();
  int woff = 0;
  for (int i = 0; i < w; ++i) woff += wt[i];
  ls[t] = woff + incl - v;
  cur[t] = ls[t];
  if (v > 0) gb[t] = baseArr[t] + atomicAdd(&bucketCursor[t], v);
  __syncthreads();
  #pragma unroll
  for (int k = 0; k < 16; ++k){
    if (bk[k] >= 0){
      int lp = atomicAdd(&cur[bk[k]], 1);
      staged[lp] = ed[k];
      bos[lp] = (unsigned char)bk[k];
    }
  }
  __syncthreads();
  int nvalid = min(4096, E - base);
  #pragma unroll
  for (int k = 0; k < 16; ++k){
    int i = k*256 + t;
    if (i < nvalid){
      int b = bos[i];
      tmp[gb[b] + (i - ls[b])] = staged[i];
    }
  }
}

// one block per bucket: group by exact dst, emit rowptr/dis/csrc
__global__ __launch_bounds__(256) void k_csr(const int2* __restrict__ tmp,
                                             const int* __restrict__ bucketHist,
                                             int* __restrict__ rowptr,
                                             float* __restrict__ dis,
                                             int* __restrict__ csrc, int N){
  __shared__ int h[256], ls[256], cur[256], baseArr[256];
  __shared__ int wt[4];
  __shared__ int stagedSrc[6144];            // cap >> max bucket size (~4350)
  int b = blockIdx.x, t = threadIdx.x, lane = t & 63, w = t >> 6;
  scan_hist(bucketHist, baseArr, wt);
  int ebase = baseArr[b];
  int cnt = bucketHist[b];
  int node0 = b << 8;
  h[t] = 0;
  __syncthreads();
  for (int i = t; i < cnt; i += 256){
    int2 e = tmp[ebase + i];
    atomicAdd(&h[e.y - node0], 1);
  }
  __syncthreads();
  int v = h[t];
  int incl = v;
  #pragma unroll
  for (int o = 1; o < 64; o <<= 1){
    int x = __shfl_up(incl, o, 64);
    if (lane >= o) incl += x;
  }
  if (lane == 63) wt[w] = incl;
  __syncthreads();
  int woff = 0;
  for (int i = 0; i < w; ++i) woff += wt[i];
  int ex = woff + incl - v;
  ls[t] = ex; cur[t] = ex;
  int d = node0 + t;
  if (d < N){
    rowptr[d+1] = ebase + ex + v;
    dis[d] = rsqrtf((float)v + 1.0f);
  }
  if (b == 0 && t == 0) rowptr[0] = 0;
  __syncthreads();
  for (int i = t; i < cnt; i += 256){
    int2 e = tmp[ebase + i];
    int lp = atomicAdd(&cur[e.y - node0], 1);
    stagedSrc[lp] = e.x;
  }
  __syncthreads();
  for (int i = t; i < cnt; i += 256)
    csrc[ebase + i] = stagedSrc[i];
}

// ------------------- GEMM: bf16 MFMA, fused BN-affine+ReLU on A, dis-scale on out ----
// MODE 0: A fp32 (= x), plain convert. MODE 1: A bf16 (= AGG), affine+relu in fp32.
// MODE 1 replica-reduce is cooperative+coalesced: 256 threads each sum
// rep[rr*256+tid] (stride-1 across lanes), affine coeffs built in LDS.
template<int MODE>
__global__ __launch_bounds__(256) void k_gemm(const void* __restrict__ Av,
                                              const ushort* __restrict__ Wf,
                                              const float* __restrict__ rep,
                                              const float* __restrict__ g,
                                              const float* __restrict__ be,
                                              const float* __restrict__ dis,
                                              ushort* __restrict__ O, int n, float invN){
  __shared__ float aL[HD], bL[HD];
  int tid = threadIdx.x;
  if (MODE){
    float s = 0.f;
    #pragma unroll 8
    for (int r = 0; r < RREP; ++r) s += rep[(size_t)r*2*HD + tid];
    if (tid < HD) aL[tid] = s; else bL[tid - HD] = s;
    __syncthreads();
    if (tid < HD){
      float m = aL[tid]*invN;
      float var = fmaxf(bL[tid]*invN - m*m, 0.f);
      float Ac = g[tid]*rsqrtf(var + EPS);
      aL[tid] = Ac; bL[tid] = be[tid] - m*Ac;
    }
    __syncthreads();
  }
  int lane = tid & 63, wave = tid >> 6;
  int quad = lane >> 4, r16 = lane & 15;
  int row = blockIdx.x*64 + wave*16 + r16;
  int rowc = min(row, n-1);
  floatx4 acc[8] = {};
  #pragma unroll
  for (int kb = 0; kb < 4; ++kb){
    int k0 = kb*32 + quad*8;
    short8 af;
    if (MODE){
      const ushort* Arow = (const ushort*)Av + (size_t)rowc*HD;
      short8 raw = *(const short8*)(Arow + k0);
      #pragma unroll
      for (int jj = 0; jj < 8; ++jj){
        float f = bf2f((ushort)raw[jj]);
        f = fmaxf(f*aL[k0+jj] + bL[k0+jj], 0.f);
        af[jj] = (short)f2bf(f);
      }
    } else {
      const float* Arow = (const float*)Av + (size_t)rowc*HD;
      float4 x0 = *(const float4*)(Arow + k0);
      float4 x1 = *(const float4*)(Arow + k0 + 4);
      af[0] = (short)f2bf(x0.x); af[1] = (short)f2bf(x0.y);
      af[2] = (short)f2bf(x0.z); af[3] = (short)f2bf(x0.w);
      af[4] = (short)f2bf(x1.x); af[5] = (short)f2bf(x1.y);
      af[6] = (short)f2bf(x1.z); af[7] = (short)f2bf(x1.w);
    }
    const ushort* wp = Wf + ((size_t)(kb*8)*64 + lane)*8;
    #pragma unroll
    for (int nt = 0; nt < 8; ++nt){
      short8 bf = *(const short8*)(wp + (size_t)nt*64*8);
      acc[nt] = __builtin_amdgcn_mfma_f32_16x16x32_bf16(af, bf, acc[nt], 0, 0, 0);
    }
  }
  int rbase = blockIdx.x*64 + wave*16 + quad*4;
  float ds[4];
  #pragma unroll
  for (int r = 0; r < 4; ++r) ds[r] = dis[min(rbase + r, n-1)];
  #pragma unroll
  for (int nt = 0; nt < 8; ++nt){
    #pragma unroll
    for (int r = 0; r < 4; ++r){
      int rr = rbase + r;
      if (rr < n) O[(size_t)rr*HD + nt*16 + r16] = f2bf(acc[nt][r]*ds[r]);
    }
  }
}

// ------------------- edge aggregation + BN stats (replicated atomics) -------------
__global__ __launch_bounds__(256) void k_gather(const ushort* __restrict__ hw,
                                                const int* __restrict__ rowptr,
                                                const int* __restrict__ csrc,
                                                const float* __restrict__ dis,
                                                ushort* __restrict__ agg,
                                                float* __restrict__ repOut, int N){
  __shared__ float2 sm[4][HD];
  int grp = threadIdx.x >> 4, j = threadIdx.x & 15;
  int wave = threadIdx.x >> 6, lane = threadIdx.x & 63;
  int i = blockIdx.x*16 + grp;
  bool valid = (i < N);
  int ic = valid ? i : N-1;
  uint4 q = ((const uint4*)(hw + (size_t)ic*HD))[j];
  float a[8];
  a[0] = bflo(q.x); a[1] = bfhi(q.x);
  a[2] = bflo(q.y); a[3] = bfhi(q.y);
  a[4] = bflo(q.z); a[5] = bfhi(q.z);
  a[6] = bflo(q.w); a[7] = bfhi(q.w);
  int e = rowptr[ic], e1 = rowptr[ic+1];
  #define ADD8(Q) \
    a[0] += bflo(Q.x); a[1] += bfhi(Q.x); \
    a[2] += bflo(Q.y); a[3] += bfhi(Q.y); \
    a[4] += bflo(Q.z); a[5] += bfhi(Q.z); \
    a[6] += bflo(Q.w); a[7] += bfhi(Q.w);
  while (e < e1 && (e & 3)){
    uint4 qq = ((const uint4*)(hw + (size_t)csrc[e]*HD))[j];
    ADD8(qq);
    e++;
  }
  int4 c0, c1;
  if (e + 8 <= e1){
    c0 = *(const int4*)&csrc[e];
    c1 = *(const int4*)&csrc[e+4];
  }
  while (e + 8 <= e1){
    int en = e + 8;
    int4 n0, n1;
    if (en + 8 <= e1){
      n0 = *(const int4*)&csrc[en];
      n1 = *(const int4*)&csrc[en+4];
    }
    uint4 q0 = ((const uint4*)(hw + (size_t)c0.x*HD))[j];
    uint4 q1 = ((const uint4*)(hw + (size_t)c0.y*HD))[j];
    uint4 q2 = ((const uint4*)(hw + (size_t)c0.z*HD))[j];
    uint4 q3 = ((const uint4*)(hw + (size_t)c0.w*HD))[j];
    uint4 q4 = ((const uint4*)(hw + (size_t)c1.x*HD))[j];
    uint4 q5 = ((const uint4*)(hw + (size_t)c1.y*HD))[j];
    uint4 q6 = ((const uint4*)(hw + (size_t)c1.z*HD))[j];
    uint4 q7 = ((const uint4*)(hw + (size_t)c1.w*HD))[j];
    ADD8(q0); ADD8(q1); ADD8(q2); ADD8(q3);
    ADD8(q4); ADD8(q5); ADD8(q6); ADD8(q7);
    c0 = n0; c1 = n1; e = en;
  }
  if (e + 4 <= e1){
    int4 tt = *(const int4*)&csrc[e];
    uint4 q0 = ((const uint4*)(hw + (size_t)tt.x*HD))[j];
    uint4 q1 = ((const uint4*)(hw + (size_t)tt.y*HD))[j];
    uint4 q2 = ((const uint4*)(hw + (size_t)tt.z*HD))[j];
    uint4 q3 = ((const uint4*)(hw + (size_t)tt.w*HD))[j];
    ADD8(q0); ADD8(q1); ADD8(q2); ADD8(q3);
    e += 4;
  }
  for (; e < e1; ++e){
    uint4 qq = ((const uint4*)(hw + (size_t)csrc[e]*HD))[j];
    ADD8(qq);
  }
  #undef ADD8
  float sc = dis[ic];
  #pragma unroll
  for (int k = 0; k < 8; ++k) a[k] *= sc;
  if (valid){
    uint4 o;
    o.x = (unsigned)f2bf(a[0]) | ((unsigned)f2bf(a[1]) << 16);
    o.y = (unsigned)f2bf(a[2]) | ((unsigned)f2bf(a[3]) << 16);
    o.z = (unsigned)f2bf(a[4]) | ((unsigned)f2bf(a[5]) << 16);
    o.w = (unsigned)f2bf(a[6]) | ((unsigned)f2bf(a[7]) << 16);
    ((uint4*)(agg + (size_t)i*HD))[j] = o;
  }
  float z = valid ? 1.f : 0.f;
  #pragma unroll
  for (int k = 0; k < 8; ++k){
    float s = a[k]*z, qq = a[k]*a[k]*z;
    s  += __shfl_xor(s, 16);  s  += __shfl_xor(s, 32);
    qq += __shfl_xor(qq, 16); qq += __shfl_xor(qq, 32);
    if (lane < 16) sm[wave][lane*8 + k] = make_float2(s, qq);
  }
  __syncthreads();
  int t = threadIdx.x;
  if (t < HD){
    float2 r0 = sm[0][t], r1 = sm[1][t], r2 = sm[2][t], r3 = sm[3][t];
    float* d = repOut + (size_t)(blockIdx.x & (RREP-1))*(2*HD);
    atomicAdd(&d[t],      r0.x + r1.x + r2.x + r3.x);
    atomicAdd(&d[HD + t], r0.y + r1.y + r2.y + r3.y);
  }
}

// ------------------- head: per-graph mean pool (BN3+ReLU) + fc1 + z-stats ---------
// replica-reduce is cooperative+coalesced (was: 512 strided loads per thread).
__global__ __launch_bounds__(256) void k_head(const ushort* __restrict__ h,
                                              const int* __restrict__ batchPtr,
                                              const float* __restrict__ rep,
                                              const float* __restrict__ gw,
                                              const float* __restrict__ be,
                                              const float* __restrict__ fcW1,
                                              const float* __restrict__ fcb1,
                                              float* __restrict__ zbuf,
                                              float* __restrict__ sums2Rep, float invN){
  __shared__ float sm[4][HD];
  __shared__ float prow[HD];
  __shared__ float abLDS[2*HD];      // [0,HD): aC, [HD,2HD): bC
  int g = blockIdx.x;
  int start = batchPtr[g], end = batchPtr[g+1];
  int tid = threadIdx.x;
  int j = tid & 15, r = tid >> 4;
  int wave = tid >> 6, lane = tid & 63;
  // cooperative coalesced replica reduction: lane-stride-1 loads
  float s = 0.f;
  #pragma unroll 8
  for (int rr = 0; rr < RREP; ++rr) s += rep[(size_t)rr*2*HD + tid];
  abLDS[tid] = s;                    // tid<HD: sum, tid>=HD: sumsq
  __syncthreads();
  if (tid < HD){
    float m = abLDS[tid]*invN;
    float var = fmaxf(abLDS[HD+tid]*invN - m*m, 0.f);
    float A = gw[tid]*rsqrtf(var + EPS);
    abLDS[tid] = A; abLDS[HD+tid] = be[tid] - m*A;
  }
  __syncthreads();
  float aC[8], bC[8];
  #pragma unroll
  for (int k = 0; k < 8; ++k){
    aC[k] = abLDS[j*8 + k];
    bC[k] = abLDS[HD + j*8 + k];
  }
  float acc[8] = {};
  for (int i = start + r; i < end; i += 16){
    uint4 q = ((const uint4*)(h + (size_t)i*HD))[j];
    acc[0] += fmaxf(bflo(q.x)*aC[0] + bC[0], 0.f);
    acc[1] += fmaxf(bfhi(q.x)*aC[1] + bC[1], 0.f);
    acc[2] += fmaxf(bflo(q.y)*aC[2] + bC[2], 0.f);
    acc[3] += fmaxf(bfhi(q.y)*aC[3] + bC[3], 0.f);
    acc[4] += fmaxf(bflo(q.z)*aC[4] + bC[4], 0.f);
    acc[5] += fmaxf(bfhi(q.z)*aC[5] + bC[5], 0.f);
    acc[6] += fmaxf(bflo(q.w)*aC[6] + bC[6], 0.f);
    acc[7] += fmaxf(bfhi(q.w)*aC[7] + bC[7], 0.f);
  }
  #pragma unroll
  for (int k = 0; k < 8; ++k){
    float ss = acc[k];
    ss += __shfl_xor(ss, 16); ss += __shfl_xor(ss, 32);
    if (lane < 16) sm[wave][lane*8 + k] = ss;
  }
  __syncthreads();
  if (tid < HD){
    float tot = sm[0][tid] + sm[1][tid] + sm[2][tid] + sm[3][tid];
    prow[tid] = tot / (float)max(end - start, 1);
  }
  __syncthreads();
  if (tid < FCD){
    float accf = 0.f;
    #pragma unroll 8
    for (int k = 0; k < HD; ++k)
      accf += prow[k] * fcW1[k*FCD + tid];
    float zv = accf + fcb1[tid];
    zbuf[(size_t)g*FCD + tid] = zv;
    float* d2 = sums2Rep + (size_t)(g & (R2-1))*(2*FCD);
    atomicAdd(&d2[tid], zv);
    atomicAdd(&d2[FCD + tid], zv*zv);
  }
}

__global__ __launch_bounds__(64) void k_final(const float* __restrict__ z,
                                              const float* __restrict__ sums2Rep,
                                              const float* __restrict__ g,
                                              const float* __restrict__ be,
                                              const float* __restrict__ w2,
                                              const float* __restrict__ b2,
                                              float* __restrict__ out, int G, float invG){
  int gg = blockIdx.x, c = threadIdx.x;
  float sS = 0.f, sQ = 0.f;
  #pragma unroll
  for (int rr = 0; rr < R2; ++rr){
    sS += sums2Rep[(size_t)rr*2*FCD + c];
    sQ += sums2Rep[(size_t)rr*2*FCD + FCD + c];
  }
  float m = sS*invG;
  float var = fmaxf(sQ*invG - m*m, 0.f);
  float A = g[c]*rsqrtf(var + EPS);
  float B = be[c] - m*A;
  float v = fmaxf(z[(size_t)gg*FCD + c]*A + B, 0.f) * w2[c];
  #pragma unroll
  for (int o = 32; o > 0; o >>= 1) v += __shfl_down(v, o, 64);
  if (c == 0) out[gg] = v + b2[0];
}

// ------------------- launch -------------------

extern "C" void kernel_launch(void* const* d_in, const int* in_sizes, int n_in,
                              void* d_out, int out_size, void* d_ws, size_t ws_size,
                              hipStream_t stream){
  const float* x    = (const float*)d_in[0];
  const int*   ei   = (const int*)d_in[1];
  const int*   batch= (const int*)d_in[2];
  const float* W1 = (const float*)d_in[3];
  const float* g1 = (const float*)d_in[5];
  const float* be1= (const float*)d_in[6];
  const float* W2 = (const float*)d_in[7];
  const float* g2 = (const float*)d_in[9];
  const float* be2= (const float*)d_in[10];
  const float* W3 = (const float*)d_in[11];
  const float* g3 = (const float*)d_in[13];
  const float* be3= (const float*)d_in[14];
  const float* fcW1 = (const float*)d_in[15];
  const float* fcb1 = (const float*)d_in[16];
  const float* fcg1 = (const float*)d_in[17];
  const float* fcbe1= (const float*)d_in[18];
  const float* fcW2 = (const float*)d_in[19];
  const float* fcb2 = (const float*)d_in[20];
  float* out = (float*)d_out;

  const int N = in_sizes[0] / HD;      // 50000
  const int E = in_sizes[1] / 2;       // 800000
  const int G = out_size;              // 500

  const int* esrc = ei;
  const int* edst = ei + E;

  char* p = (char*)d_ws;
  auto alloc = [&](size_t bytes)->void*{
    void* r = (void*)p; p += (bytes + 255) & ~(size_t)255; return r;
  };
  int gatherBlocks = (N + 15)/16;
  int nEB = (E + 4095)/4096;           // 196 edge blocks
  int nBB = (N + 255)/256;             // 196 batch-ptr blocks
  int NB  = (N + 255)/256;             // 196 node buckets (<=256 required)

  // zeroed region: bucketHist | bucketCursor | sumsRep[3][RREP][2*HD] | sums2Rep[R2][2*FCD]
  int ZW = 512 + 3*RREP*2*HD + R2*2*FCD;
  int*    zeroBase = (int*) alloc((size_t)ZW*4);
  int*    bucketHist   = zeroBase;
  int*    bucketCursor = zeroBase + 256;
  float*  sumsRep  = (float*)(zeroBase + 512);
  float*  sums2Rep = sumsRep + 3*RREP*2*HD;
  int*    batchPtr = (int*) alloc((size_t)(G+1)*4);
  int2*   tmp    = (int2*)  alloc((size_t)E*8);
  int*    rowptr = (int*)   alloc((size_t)(N+1)*4);
  int*    csrc   = (int*)   alloc((size_t)E*4);
  float*  dis    = (float*) alloc((size_t)N*4);
  ushort* HWb    = (ushort*)alloc((size_t)N*HD*2);
  ushort* AGG    = (ushort*)alloc((size_t)N*HD*2);
  ushort* Wf     = (ushort*)alloc((size_t)3*HD*HD*2);
  float*  zbuf   = (float*) alloc((size_t)G*FCD*4);

  float invN = 1.0f/(float)N, invG = 1.0f/(float)G;

  hipMemsetAsync(zeroBase, 0, (size_t)ZW*4, stream);
  k_setup <<<nEB + nBB + 3*(HD*HD/256), 256, 0, stream>>>(
      edst, bucketHist, E, nEB, batch, batchPtr, N, G, nBB, W1, W2, W3, Wf);
  k_bucket<<<nEB, 256, 0, stream>>>(esrc, edst, bucketHist, bucketCursor, tmp, E);
  k_csr   <<<NB, 256, 0, stream>>>(tmp, bucketHist, rowptr, dis, csrc, N);

  int gemmBlocks = (N + 63)/64;

  // layer 1
  k_gemm<0> <<<gemmBlocks, 256, 0, stream>>>(x,   Wf,         nullptr, nullptr, nullptr, dis, HWb, N, invN);
  k_gather  <<<gatherBlocks, 256, 0, stream>>>(HWb, rowptr, csrc, dis, AGG, sumsRep, N);
  // layer 2 (BN1+ReLU fused into A-load)
  k_gemm<1> <<<gemmBlocks, 256, 0, stream>>>(AGG, Wf + 16384, sumsRep, g1, be1, dis, HWb, N, invN);
  k_gather  <<<gatherBlocks, 256, 0, stream>>>(HWb, rowptr, csrc, dis, AGG, sumsRep + (size_t)RREP*2*HD, N);
  // layer 3 (BN2+ReLU fused into A-load)
  k_gemm<1> <<<gemmBlocks, 256, 0, stream>>>(AGG, Wf + 32768, sumsRep + (size_t)RREP*2*HD, g2, be2, dis, HWb, N, invN);
  k_gather  <<<gatherBlocks, 256, 0, stream>>>(HWb, rowptr, csrc, dis, AGG, sumsRep + (size_t)2*RREP*2*HD, N);

  // head: pool(BN3+ReLU) + fc1 + stats, then BN+fc2
  k_head  <<<G, 256, 0, stream>>>(AGG, batchPtr, sumsRep + (size_t)2*RREP*2*HD, g3, be3,
                                  fcW1, fcb1, zbuf, sums2Rep, invN);
  k_final <<<G, FCD, 0, stream>>>(zbuf, sums2Rep, fcg1, fcbe1, fcW2, fcb2, out, G, invG);
}